// Round 11
// baseline (191.036 us; speedup 1.0000x reference)
//
#include <hip/hip_runtime.h>
#include <hip/hip_bf16.h>

#define NTOK 32768     // 2*128*128 pixel tokens
#define LOG2E 1.4426950408889634f

typedef __attribute__((ext_vector_type(8))) short bf16x8;
typedef __attribute__((ext_vector_type(4))) float f32x4;

__device__ __forceinline__ float bf2f(unsigned short u) {
  return __uint_as_float(((unsigned int)u) << 16);
}
__device__ __forceinline__ unsigned short f2bf(float f) {
  union { __hip_bfloat16 h; unsigned short u; } cv;
  cv.h = __float2bfloat16(f);
  return cv.u;
}
// HW packed f32x2 -> bf16x2 (RNE), single VALU op.
__device__ __forceinline__ unsigned cvt_pk_bf16(float lo, float hi) {
  unsigned r;
  asm("v_cvt_pk_bf16_f32 %0, %1, %2" : "=v"(r) : "v"(lo), "v"(hi));
  return r;
}
__device__ __forceinline__ float fast_exp2(float x) {
#if __has_builtin(__builtin_amdgcn_exp2f)
  return __builtin_amdgcn_exp2f(x);
#else
  return exp2f(x);
#endif
}

__device__ __forceinline__ void gload16(const void* g, void* l) {
  __builtin_amdgcn_global_load_lds(
      (const __attribute__((address_space(1))) unsigned int*)(unsigned long long)g,
      (__attribute__((address_space(3))) unsigned int*)(unsigned long long)l, 16, 0, 0);
}

// ---------------- fused prep: x->bf16 | pool(from f32) | W transpose ----------------
// blocks [0,6144): convert_x; [6144,8544): pool; [8544,9120): transpose_w.
// pool reads f32 x directly (independent of xb) so all three phases co-schedule.
__global__ __launch_bounds__(256) void prep_kernel(
    const float* __restrict__ x, unsigned short* __restrict__ xb,
    unsigned short* __restrict__ P,
    const float* __restrict__ Wq, const float* __restrict__ Wk,
    const float* __restrict__ Wv, const float* __restrict__ Wo,
    unsigned short* __restrict__ Wt) {
  __shared__ float tile[32][33];
  const int bid = blockIdx.x;
  const int t = threadIdx.x;

  if (bid < 6144) {            // ---- convert_x ----
    const int i = (bid * 256 + t) * 8;
    float4 a = *(const float4*)(x + i);
    float4 b = *(const float4*)(x + i + 4);
    *(ushort4*)(xb + i)     = make_ushort4(f2bf(a.x), f2bf(a.y), f2bf(a.z), f2bf(a.w));
    *(ushort4*)(xb + i + 4) = make_ushort4(f2bf(b.x), f2bf(b.y), f2bf(b.z), f2bf(b.w));
  } else if (bid < 8544) {     // ---- pool (f32 in, bf16 out), 8ch/thread ----
    const int unit = (bid - 6144) * 256 + t;   // 614400 = 12800 cells * 48
    const int cell = unit / 48;
    const int c8 = (unit - cell * 48) * 8;
    const int b = cell / 6400;
    const int rem = cell - b * 6400;
    const int p0 = rem / 80, p1 = rem - p0 * 80;
    const int i0 = 2 * p0 - 16, i1 = i0 + 1;
    const int j0 = 2 * p1 - 16, j1 = j0 + 1;
    const int r0 = i0 < 0 ? -i0 : (i0 > 127 ? 254 - i0 : i0);
    const int r1 = i1 < 0 ? -i1 : (i1 > 127 ? 254 - i1 : i1);
    const int c0 = j0 < 0 ? -j0 : (j0 > 127 ? 254 - j0 : j0);
    const int c1 = j1 < 0 ? -j1 : (j1 > 127 ? 254 - j1 : j1);
    const float* s00 = x + ((size_t)((b * 128 + r0) * 128 + c0)) * 384 + c8;
    const float* s01 = x + ((size_t)((b * 128 + r0) * 128 + c1)) * 384 + c8;
    const float* s10 = x + ((size_t)((b * 128 + r1) * 128 + c0)) * 384 + c8;
    const float* s11 = x + ((size_t)((b * 128 + r1) * 128 + c1)) * 384 + c8;
    float4 a0 = *(const float4*)s00, a1 = *(const float4*)(s00 + 4);
    float4 b0 = *(const float4*)s01, b1 = *(const float4*)(s01 + 4);
    float4 c0v = *(const float4*)s10, c1v = *(const float4*)(s10 + 4);
    float4 d0 = *(const float4*)s11, d1 = *(const float4*)(s11 + 4);
    ushort4 lo = make_ushort4(f2bf(0.25f * (a0.x + b0.x + c0v.x + d0.x)),
                              f2bf(0.25f * (a0.y + b0.y + c0v.y + d0.y)),
                              f2bf(0.25f * (a0.z + b0.z + c0v.z + d0.z)),
                              f2bf(0.25f * (a0.w + b0.w + c0v.w + d0.w)));
    ushort4 hi = make_ushort4(f2bf(0.25f * (a1.x + b1.x + c1v.x + d1.x)),
                              f2bf(0.25f * (a1.y + b1.y + c1v.y + d1.y)),
                              f2bf(0.25f * (a1.z + b1.z + c1v.z + d1.z)),
                              f2bf(0.25f * (a1.w + b1.w + c1v.w + d1.w)));
    *(ushort4*)(P + (size_t)cell * 384 + c8) = lo;
    *(ushort4*)(P + (size_t)cell * 384 + c8 + 4) = hi;
  } else {                     // ---- transpose_w ----
    const int idx = bid - 8544;          // [0,576): wsel*144 + (n0/32)*12 + (k0/32)
    const int wsel = idx / 144;
    const int r2 = idx - wsel * 144;
    const int k0 = (r2 % 12) * 32, n0 = (r2 / 12) * 32;
    const float* W = (wsel == 0) ? Wq : (wsel == 1) ? Wk : (wsel == 2) ? Wv : Wo;
    unsigned short* out = Wt + (size_t)wsel * 147456;
    const int r = t >> 3, c4 = (t & 7) * 4;
    float4 v = *(const float4*)&W[(size_t)(k0 + r) * 384 + n0 + c4];
    tile[r][c4 + 0] = v.x; tile[r][c4 + 1] = v.y; tile[r][c4 + 2] = v.z; tile[r][c4 + 3] = v.w;
    __syncthreads();
    ushort4 o = make_ushort4(f2bf(tile[c4 + 0][r]), f2bf(tile[c4 + 1][r]),
                             f2bf(tile[c4 + 2][r]), f2bf(tile[c4 + 3][r]));
    *(ushort4*)&out[(size_t)(n0 + r) * 384 + k0 + c4] = o;
  }
}

// ---------------- fused QKV (+pooled KV) projection, 2-phase pipelined ----------------
__global__ __launch_bounds__(256) void mfma_proj_fused(
    const unsigned short* __restrict__ xb, const unsigned short* __restrict__ P,
    const unsigned short* __restrict__ Wt,
    const float* __restrict__ bq, const float* __restrict__ bk, const float* __restrict__ bv,
    unsigned short* __restrict__ Qb, unsigned short* __restrict__ Kcat,
    unsigned short* __restrict__ Vcat) {
  const int bid = blockIdx.x;
  const unsigned short* X;
  int wsel, colblk, yy; size_t off;
  if (bid < 2304) {
    const int xx = bid % 9; yy = bid / 9;
    X = xb; wsel = xx / 3; colblk = xx % 3; off = 0;
  } else {
    const int r = bid - 2304; const int xx = r % 6; yy = r / 6;
    X = P; wsel = 1 + xx / 3; colblk = xx % 3; off = (size_t)NTOK * 384;
  }
  const float* bias = (wsel == 0) ? bq : (wsel == 1) ? bk : bv;
  unsigned short* Y = ((wsel == 0) ? Qb : (wsel == 1) ? Kcat : Vcat) + off;
  const unsigned short* Wm = Wt + (size_t)wsel * 147456;
  const int n0 = colblk * 128;
  const int m0 = yy * 128;

  __shared__ __attribute__((aligned(16))) unsigned short As[2][128 * 32];
  __shared__ __attribute__((aligned(16))) unsigned short Bs[2][128 * 32];
  const int t = threadIdx.x;
  const int w = t >> 6, l = t & 63, l15 = l & 15, g = l >> 4;
  const int wm = w >> 1, wn = w & 1;
  const int srow = (w * 2) * 16 + (l >> 2), srow2 = (w * 2 + 1) * 16 + (l >> 2);
  const int skc = (l & 3) * 8;

  f32x4 acc[4][4];
  #pragma unroll
  for (int i = 0; i < 4; ++i)
    #pragma unroll
    for (int j = 0; j < 4; ++j) acc[i][j] = {0.f, 0.f, 0.f, 0.f};

  {
    gload16(X  + (size_t)(m0 + srow)  * 384 + skc, &As[0][(w * 2)     * 512]);
    gload16(X  + (size_t)(m0 + srow2) * 384 + skc, &As[0][(w * 2 + 1) * 512]);
    gload16(Wm + (size_t)(n0 + srow)  * 384 + skc, &Bs[0][(w * 2)     * 512]);
    gload16(Wm + (size_t)(n0 + srow2) * 384 + skc, &Bs[0][(w * 2 + 1) * 512]);
  }
  asm volatile("s_waitcnt vmcnt(0)" ::: "memory");
  __builtin_amdgcn_s_barrier();
  __builtin_amdgcn_sched_barrier(0);

  int cur = 0;
  for (int kt = 0; kt < 12; ++kt) {
    if (kt < 11) {
      const int k0 = (kt + 1) * 32;
      gload16(X  + (size_t)(m0 + srow)  * 384 + k0 + skc, &As[cur ^ 1][(w * 2)     * 512]);
      gload16(X  + (size_t)(m0 + srow2) * 384 + k0 + skc, &As[cur ^ 1][(w * 2 + 1) * 512]);
      gload16(Wm + (size_t)(n0 + srow)  * 384 + k0 + skc, &Bs[cur ^ 1][(w * 2)     * 512]);
      gload16(Wm + (size_t)(n0 + srow2) * 384 + k0 + skc, &Bs[cur ^ 1][(w * 2 + 1) * 512]);
    }
    bf16x8 af[4], bfr[4];
    #pragma unroll
    for (int mi = 0; mi < 4; ++mi)
      af[mi] = *(const bf16x8*)(&As[cur][(wm * 64 + mi * 16 + l15) * 32 + g * 8]);
    #pragma unroll
    for (int nj = 0; nj < 4; ++nj)
      bfr[nj] = *(const bf16x8*)(&Bs[cur][(wn * 64 + nj * 16 + l15) * 32 + g * 8]);
    #pragma unroll
    for (int mi = 0; mi < 4; ++mi)
      #pragma unroll
      for (int nj = 0; nj < 4; ++nj)
        acc[mi][nj] = __builtin_amdgcn_mfma_f32_16x16x32_bf16(af[mi], bfr[nj], acc[mi][nj], 0, 0, 0);
    if (kt < 11) {
      asm volatile("s_waitcnt vmcnt(0)" ::: "memory");
      __builtin_amdgcn_s_barrier();
      __builtin_amdgcn_sched_barrier(0);
      cur ^= 1;
    }
  }

  float bv4[4];
  #pragma unroll
  for (int nj = 0; nj < 4; ++nj) bv4[nj] = bias[n0 + wn * 64 + nj * 16 + l15];
  #pragma unroll
  for (int mi = 0; mi < 4; ++mi)
    #pragma unroll
    for (int nj = 0; nj < 4; ++nj)
      #pragma unroll
      for (int r = 0; r < 4; ++r) {
        const size_t row = m0 + wm * 64 + mi * 16 + g * 4 + r;
        const size_t col = n0 + wn * 64 + nj * 16 + l15;
        Y[row * 384 + col] = f2bf(acc[mi][nj][r] + bv4[nj]);
      }
}

// ---------------- final output projection (f32 out), 2-phase pipelined ----------------
__global__ __launch_bounds__(256) void mfma_proj_out(const unsigned short* __restrict__ X,
                                                     const unsigned short* __restrict__ Wm,
                                                     const float* __restrict__ bias,
                                                     float* __restrict__ Y) {
  const int n0 = blockIdx.x * 128, m0 = blockIdx.y * 128;
  __shared__ __attribute__((aligned(16))) unsigned short As[2][128 * 32];
  __shared__ __attribute__((aligned(16))) unsigned short Bs[2][128 * 32];
  const int t = threadIdx.x;
  const int w = t >> 6, l = t & 63, l15 = l & 15, g = l >> 4;
  const int wm = w >> 1, wn = w & 1;
  const int srow = (w * 2) * 16 + (l >> 2), srow2 = (w * 2 + 1) * 16 + (l >> 2);
  const int skc = (l & 3) * 8;

  f32x4 acc[4][4];
  #pragma unroll
  for (int i = 0; i < 4; ++i)
    #pragma unroll
    for (int j = 0; j < 4; ++j) acc[i][j] = {0.f, 0.f, 0.f, 0.f};

  {
    gload16(X  + (size_t)(m0 + srow)  * 384 + skc, &As[0][(w * 2)     * 512]);
    gload16(X  + (size_t)(m0 + srow2) * 384 + skc, &As[0][(w * 2 + 1) * 512]);
    gload16(Wm + (size_t)(n0 + srow)  * 384 + skc, &Bs[0][(w * 2)     * 512]);
    gload16(Wm + (size_t)(n0 + srow2) * 384 + skc, &Bs[0][(w * 2 + 1) * 512]);
  }
  asm volatile("s_waitcnt vmcnt(0)" ::: "memory");
  __builtin_amdgcn_s_barrier();
  __builtin_amdgcn_sched_barrier(0);

  int cur = 0;
  for (int kt = 0; kt < 12; ++kt) {
    if (kt < 11) {
      const int k0 = (kt + 1) * 32;
      gload16(X  + (size_t)(m0 + srow)  * 384 + k0 + skc, &As[cur ^ 1][(w * 2)     * 512]);
      gload16(X  + (size_t)(m0 + srow2) * 384 + k0 + skc, &As[cur ^ 1][(w * 2 + 1) * 512]);
      gload16(Wm + (size_t)(n0 + srow)  * 384 + k0 + skc, &Bs[cur ^ 1][(w * 2)     * 512]);
      gload16(Wm + (size_t)(n0 + srow2) * 384 + k0 + skc, &Bs[cur ^ 1][(w * 2 + 1) * 512]);
    }
    bf16x8 af[4], bfr[4];
    #pragma unroll
    for (int mi = 0; mi < 4; ++mi)
      af[mi] = *(const bf16x8*)(&As[cur][(wm * 64 + mi * 16 + l15) * 32 + g * 8]);
    #pragma unroll
    for (int nj = 0; nj < 4; ++nj)
      bfr[nj] = *(const bf16x8*)(&Bs[cur][(wn * 64 + nj * 16 + l15) * 32 + g * 8]);
    #pragma unroll
    for (int mi = 0; mi < 4; ++mi)
      #pragma unroll
      for (int nj = 0; nj < 4; ++nj)
        acc[mi][nj] = __builtin_amdgcn_mfma_f32_16x16x32_bf16(af[mi], bfr[nj], acc[mi][nj], 0, 0, 0);
    if (kt < 11) {
      asm volatile("s_waitcnt vmcnt(0)" ::: "memory");
      __builtin_amdgcn_s_barrier();
      __builtin_amdgcn_sched_barrier(0);
      cur ^= 1;
    }
  }

  float bv4[4];
  #pragma unroll
  for (int nj = 0; nj < 4; ++nj) bv4[nj] = bias[n0 + wn * 64 + nj * 16 + l15];
  #pragma unroll
  for (int mi = 0; mi < 4; ++mi)
    #pragma unroll
    for (int nj = 0; nj < 4; ++nj)
      #pragma unroll
      for (int r = 0; r < 4; ++r) {
        const size_t row = m0 + wm * 64 + mi * 16 + g * 4 + r;
        const size_t col = n0 + wn * 64 + nj * 16 + l15;
        Y[row * 384 + col] = acc[mi][nj][r] + bv4[nj];
      }
}

// ---------------- MFMA flash attention (R7/R10 config + XCD-aware swizzle) ----------------
// XCD swizzle (T1): all 8 head-blocks of one window share bid%8 -> same XCD L2,
// so the window's ~147KB KV is fetched once per XCD instead of 8 times across XCDs.
// head = (bid>>3)&7, win = (bid&7) + 8*(bid>>6)  (bijective over 1024 blocks).
__global__ __launch_bounds__(256) void attn_mfma(const unsigned short* __restrict__ Qg,
                                                 const unsigned short* __restrict__ Kc,
                                                 const unsigned short* __restrict__ Vc,
                                                 const float* __restrict__ pb,
                                                 unsigned short* __restrict__ AttO) {
  __shared__ unsigned short kvb[768];   // token ids (< 45568)
  __shared__ float tb2s[12];
  __shared__ __attribute__((aligned(16))) unsigned short Ks[2][3072];    // [buf][ch][tok][8]
  __shared__ __attribute__((aligned(16))) unsigned short Vt[2][64 * 68]; // [buf][d+ones][kv]

  const int t = threadIdx.x;
  const int bid = blockIdx.x;
  const int head = (bid >> 3) & 7;
  const int win  = (bid & 7) + 8 * (bid >> 6);
  const int b = win >> 6, wrem = win & 63, wi = wrem >> 3, wj = wrem & 7;
  const int w = t >> 6, l = t & 63, l15 = l & 15, g = l >> 4;
  const int hb = head * 48;

  for (int j = t; j < 768; j += 256) {
    int o, within;
    if (j < 256)      { o = j >> 6;               within = j & 63; }
    else if (j < 512) { o = 4;                    within = j - 256; }
    else              { o = 5 + ((j - 512) >> 6); within = j & 63; }
    int tok;
    if (o == 4) {
      int r = within >> 4, c = within & 15;
      tok = (b * 128 + wi * 16 + r) * 128 + wj * 16 + c;
    } else {
      int di = o / 3 - 1, dj = o - (o / 3) * 3 - 1;
      int t0 = within >> 3, t1 = within & 7;
      int p0 = 8 * (1 + di + wi) + t0, p1 = 8 * (1 + dj + wj) + t1;
      tok = NTOK + (b * 80 + p0) * 80 + p1;
    }
    kvb[j] = (unsigned short)tok;
  }
  if (t < 12) {
    int o = (t < 4) ? t : ((t < 8) ? 4 : t - 3);
    tb2s[t] = (o == 4) ? 0.0f : (-pb[head * 9 + o] * LOG2E);
  }
  for (int idx = t; idx < 2 * 16 * 68; idx += 256) {
    const int bu = idx / 1088, rem = idx - bu * 1088;
    const int rr = rem / 68, cc = rem - rr * 68;
    Vt[bu][(48 + rr) * 68 + cc] = (rr == 0) ? 0x3F80 : 0;
  }

  const float SCALE2 = 0.14433756729740643f * LOG2E;  // 48^-0.5 * log2e
  const bf16x8 z8 = {0, 0, 0, 0, 0, 0, 0, 0};

  bf16x8 qf[4][2];
  #pragma unroll
  for (int nf = 0; nf < 4; ++nf) {
    const int tok = ((b * 128 + wi * 16 + w * 4 + nf) * 128 + wj * 16 + l15);
    const unsigned short* qp = Qg + (size_t)tok * 384 + hb;
    qf[nf][0] = *(const bf16x8*)(qp + g * 8);
    qf[nf][1] = (g < 2) ? *(const bf16x8*)(qp + 32 + g * 8) : z8;
  }

  f32x4 Oacc[4][4];
  #pragma unroll
  for (int mo = 0; mo < 4; ++mo)
    #pragma unroll
    for (int nf = 0; nf < 4; ++nf) Oacc[mo][nf] = {0.f, 0.f, 0.f, 0.f};

  __syncthreads();   // kvb / tb2s / ones rows ready

  uint4 va0, va1;
  {
    const int kvb0 = (int)kvb[l] * 384 + hb;
    gload16(Kc + kvb0 + w * 8, &Ks[0][w * 512]);
    if (w < 2) gload16(Kc + kvb0 + (4 + w) * 8, &Ks[0][(4 + w) * 512]);
    va0 = *(const uint4*)(Vc + kvb0 + w * 8);
    va1 = (w < 2) ? *(const uint4*)(Vc + kvb0 + (4 + w) * 8) : make_uint4(0, 0, 0, 0);
  }

  for (int T = 0; T < 12; ++T) {
    const int buf = T & 1;
    asm volatile("s_waitcnt vmcnt(0)" ::: "memory");   // K_T in LDS, V_T in regs
    {
      const unsigned short* u0 = (const unsigned short*)&va0;
      #pragma unroll
      for (int s = 0; s < 8; ++s) Vt[buf][(w * 8 + s) * 68 + l] = u0[s];
      if (w < 2) {
        const unsigned short* u1 = (const unsigned short*)&va1;
        #pragma unroll
        for (int s = 0; s < 8; ++s) Vt[buf][((4 + w) * 8 + s) * 68 + l] = u1[s];
      }
    }
    __syncthreads();   // all waves: K_T drained, V_T written, compute T-1 done
    if (T < 11) {
      const int kvb2 = (int)kvb[(T + 1) * 64 + l] * 384 + hb;
      gload16(Kc + kvb2 + w * 8, &Ks[buf ^ 1][w * 512]);
      if (w < 2) gload16(Kc + kvb2 + (4 + w) * 8, &Ks[buf ^ 1][(4 + w) * 512]);
      va0 = *(const uint4*)(Vc + kvb2 + w * 8);
      if (w < 2) va1 = *(const uint4*)(Vc + kvb2 + (4 + w) * 8);
    }

    const float tb = tb2s[T];
    #pragma unroll
    for (int h = 0; h < 2; ++h) {
      bf16x8 ka[2][2];
      #pragma unroll
      for (int mi = 0; mi < 2; ++mi) {
        const int krow = h * 32 + mi * 16 + l15;
        ka[mi][0] = *(const bf16x8*)&Ks[buf][g * 512 + krow * 8];
        ka[mi][1] = *(const bf16x8*)&Ks[buf][(4 + (g & 1)) * 512 + krow * 8];
      }
      f32x4 sf[2][4];
      #pragma unroll
      for (int mi = 0; mi < 2; ++mi)
        #pragma unroll
        for (int nf = 0; nf < 4; ++nf) sf[mi][nf] = {0.f, 0.f, 0.f, 0.f};
      __builtin_amdgcn_s_setprio(1);
      #pragma unroll
      for (int mi = 0; mi < 2; ++mi)
        #pragma unroll
        for (int nf = 0; nf < 4; ++nf) {
          sf[mi][nf] = __builtin_amdgcn_mfma_f32_16x16x32_bf16(ka[mi][0], qf[nf][0], sf[mi][nf], 0, 0, 0);
          sf[mi][nf] = __builtin_amdgcn_mfma_f32_16x16x32_bf16(ka[mi][1], qf[nf][1], sf[mi][nf], 0, 0, 0);
        }
      __builtin_amdgcn_s_setprio(0);

      bf16x8 pbf[4];
      #pragma unroll
      for (int nf = 0; nf < 4; ++nf) {
        float p[8];
        #pragma unroll
        for (int r = 0; r < 4; ++r) {
          p[r]     = fast_exp2(fmaf(sf[0][nf][r], SCALE2, tb));
          p[4 + r] = fast_exp2(fmaf(sf[1][nf][r], SCALE2, tb));
        }
        unsigned a0 = cvt_pk_bf16(p[0], p[1]);
        unsigned a1 = cvt_pk_bf16(p[2], p[3]);
        unsigned b0 = cvt_pk_bf16(p[4], p[5]);
        unsigned b1 = cvt_pk_bf16(p[6], p[7]);
        asm("v_permlane32_swap_b32 %0, %1" : "+v"(a0), "+v"(b0));
        asm("v_permlane32_swap_b32 %0, %1" : "+v"(a1), "+v"(b1));
        asm("v_permlane16_swap_b32 %0, %1" : "+v"(a0), "+v"(b0));
        asm("v_permlane16_swap_b32 %0, %1" : "+v"(a1), "+v"(b1));
        union { bf16x8 v; unsigned u[4]; } cv;
        cv.u[0] = a0; cv.u[1] = a1; cv.u[2] = b0; cv.u[3] = b1;
        pbf[nf] = cv.v;
      }

      #pragma unroll
      for (int mo = 0; mo < 4; ++mo) {
        const unsigned short* vp = &Vt[buf][(mo * 16 + l15) * 68 + h * 32 + g * 8];
        union { bf16x8 v; ushort4 u[2]; } cv;
        cv.u[0] = *(const ushort4*)vp;
        cv.u[1] = *(const ushort4*)(vp + 4);
        bf16x8 va = cv.v;
        __builtin_amdgcn_s_setprio(1);
        #pragma unroll
        for (int nf = 0; nf < 4; ++nf)
          Oacc[mo][nf] = __builtin_amdgcn_mfma_f32_16x16x32_bf16(va, pbf[nf], Oacc[mo][nf], 0, 0, 0);
        __builtin_amdgcn_s_setprio(0);
      }
    }
  }

  #pragma unroll
  for (int nf = 0; nf < 4; ++nf) {
    const float denom = __shfl(Oacc[3][nf][0], l15, 64);
    const float inv = 1.0f / denom;
    const int tok = ((b * 128 + wi * 16 + w * 4 + nf) * 128 + wj * 16 + l15);
    unsigned short* op = AttO + (size_t)tok * 384 + hb;
    #pragma unroll
    for (int mo = 0; mo < 3; ++mo) {
      uint2 u;
      u.x = cvt_pk_bf16(Oacc[mo][nf][0] * inv, Oacc[mo][nf][1] * inv);
      u.y = cvt_pk_bf16(Oacc[mo][nf][2] * inv, Oacc[mo][nf][3] * inv);
      *(uint2*)(op + mo * 16 + g * 4) = u;
    }
  }
}

extern "C" void kernel_launch(void* const* d_in, const int* in_sizes, int n_in,
                              void* d_out, int out_size, void* d_ws, size_t ws_size,
                              hipStream_t stream) {
  const float* x  = (const float*)d_in[0];
  const float* Wq = (const float*)d_in[1];
  const float* bq = (const float*)d_in[2];
  const float* Wk = (const float*)d_in[3];
  const float* bk = (const float*)d_in[4];
  const float* Wv = (const float*)d_in[5];
  const float* bv = (const float*)d_in[6];
  const float* Wo = (const float*)d_in[7];
  const float* bo = (const float*)d_in[8];
  const float* pb = (const float*)d_in[9];

  // ws layout (bytes), total ~106 MB (see R3 comment); Qb lives in d_out's first half.
  char* ws = (char*)d_ws;
  unsigned short* Wt   = (unsigned short*)(ws);
  unsigned short* P    = (unsigned short*)(ws + 1179648ull);
  unsigned short* Kcat = (unsigned short*)(ws + 11010048ull);
  unsigned short* Vcat = (unsigned short*)(ws + 46006272ull);
  unsigned short* xb   = (unsigned short*)(ws + 81002496ull);
  unsigned short* AttO = xb;
  unsigned short* Qb   = (unsigned short*)d_out;

  prep_kernel<<<9120, 256, 0, stream>>>(x, xb, P, Wq, Wk, Wv, Wo, Wt);
  mfma_proj_fused<<<2904, 256, 0, stream>>>(xb, P, Wt, bq, bk, bv, Qb, Kcat, Vcat);
  attn_mfma<<<1024, 256, 0, stream>>>(Qb, Kcat, Vcat, pb, AttO);
  mfma_proj_out<<<dim3(3, 256), 256, 0, stream>>>(AttO, Wt + 3 * 147456, bo, (float*)d_out);
}

// Round 12
// 186.661 us; speedup vs baseline: 1.0234x; 1.0234x over previous
//
#include <hip/hip_runtime.h>
#include <hip/hip_bf16.h>

#define NTOK 32768     // 2*128*128 pixel tokens
#define LOG2E 1.4426950408889634f

typedef __attribute__((ext_vector_type(8))) short bf16x8;
typedef __attribute__((ext_vector_type(4))) float f32x4;

__device__ __forceinline__ float bf2f(unsigned short u) {
  return __uint_as_float(((unsigned int)u) << 16);
}
__device__ __forceinline__ unsigned short f2bf(float f) {
  union { __hip_bfloat16 h; unsigned short u; } cv;
  cv.h = __float2bfloat16(f);
  return cv.u;
}
// HW packed f32x2 -> bf16x2 (RNE), single VALU op.
__device__ __forceinline__ unsigned cvt_pk_bf16(float lo, float hi) {
  unsigned r;
  asm("v_cvt_pk_bf16_f32 %0, %1, %2" : "=v"(r) : "v"(lo), "v"(hi));
  return r;
}
__device__ __forceinline__ float fast_exp2(float x) {
#if __has_builtin(__builtin_amdgcn_exp2f)
  return __builtin_amdgcn_exp2f(x);
#else
  return exp2f(x);
#endif
}

__device__ __forceinline__ void gload16(const void* g, void* l) {
  __builtin_amdgcn_global_load_lds(
      (const __attribute__((address_space(1))) unsigned int*)(unsigned long long)g,
      (__attribute__((address_space(3))) unsigned int*)(unsigned long long)l, 16, 0, 0);
}

// ---------------- x f32 -> bf16 ----------------
__global__ __launch_bounds__(256) void convert_x(const float* __restrict__ x,
                                                 unsigned short* __restrict__ xb) {
  const int i = (blockIdx.x * 256 + threadIdx.x) * 8;
  float4 a = *(const float4*)(x + i);
  float4 b = *(const float4*)(x + i + 4);
  *(ushort4*)(xb + i)     = make_ushort4(f2bf(a.x), f2bf(a.y), f2bf(a.z), f2bf(a.w));
  *(ushort4*)(xb + i + 4) = make_ushort4(f2bf(b.x), f2bf(b.y), f2bf(b.z), f2bf(b.w));
}

// ---------------- W[k][n] f32 -> Wt[n][k] bf16, 4 matrices ----------------
__global__ __launch_bounds__(256) void transpose_w(const float* __restrict__ Wq,
                                                   const float* __restrict__ Wk,
                                                   const float* __restrict__ Wv,
                                                   const float* __restrict__ Wo,
                                                   unsigned short* __restrict__ Wt) {
  __shared__ float tile[32][33];
  const int wsel = blockIdx.z;
  const float* W = (wsel == 0) ? Wq : (wsel == 1) ? Wk : (wsel == 2) ? Wv : Wo;
  unsigned short* out = Wt + (size_t)wsel * 147456;
  const int k0 = blockIdx.x * 32, n0 = blockIdx.y * 32;
  const int r = threadIdx.x >> 3, c4 = (threadIdx.x & 7) * 4;
  float4 v = *(const float4*)&W[(size_t)(k0 + r) * 384 + n0 + c4];
  tile[r][c4 + 0] = v.x; tile[r][c4 + 1] = v.y; tile[r][c4 + 2] = v.z; tile[r][c4 + 3] = v.w;
  __syncthreads();
  ushort4 o = make_ushort4(f2bf(tile[c4 + 0][r]), f2bf(tile[c4 + 1][r]),
                           f2bf(tile[c4 + 2][r]), f2bf(tile[c4 + 3][r]));
  *(ushort4*)&out[(size_t)(n0 + r) * 384 + k0 + c4] = o;
}

// ---------------- pooled map P (bf16 in, bf16 out), vectorized 8ch/thread ----------------
__global__ __launch_bounds__(192) void pool_kernel(const unsigned short* __restrict__ xb,
                                                   unsigned short* __restrict__ P) {
  const int unit = blockIdx.x * 192 + threadIdx.x;
  const int cell = unit / 48;
  const int c8 = (unit - cell * 48) * 8;
  const int b = cell / 6400;
  const int rem = cell - b * 6400;
  const int p0 = rem / 80, p1 = rem - p0 * 80;
  const int i0 = 2 * p0 - 16, i1 = i0 + 1;
  const int j0 = 2 * p1 - 16, j1 = j0 + 1;
  const int r0 = i0 < 0 ? -i0 : (i0 > 127 ? 254 - i0 : i0);
  const int r1 = i1 < 0 ? -i1 : (i1 > 127 ? 254 - i1 : i1);
  const int c0 = j0 < 0 ? -j0 : (j0 > 127 ? 254 - j0 : j0);
  const int c1 = j1 < 0 ? -j1 : (j1 > 127 ? 254 - j1 : j1);
  uint4 u00 = *(const uint4*)(xb + ((size_t)((b * 128 + r0) * 128 + c0)) * 384 + c8);
  uint4 u01 = *(const uint4*)(xb + ((size_t)((b * 128 + r0) * 128 + c1)) * 384 + c8);
  uint4 u10 = *(const uint4*)(xb + ((size_t)((b * 128 + r1) * 128 + c0)) * 384 + c8);
  uint4 u11 = *(const uint4*)(xb + ((size_t)((b * 128 + r1) * 128 + c1)) * 384 + c8);
  const unsigned short* a0 = (const unsigned short*)&u00;
  const unsigned short* a1 = (const unsigned short*)&u01;
  const unsigned short* a2 = (const unsigned short*)&u10;
  const unsigned short* a3 = (const unsigned short*)&u11;
  unsigned short o[8];
  #pragma unroll
  for (int j = 0; j < 8; ++j)
    o[j] = f2bf(0.25f * (bf2f(a0[j]) + bf2f(a1[j]) + bf2f(a2[j]) + bf2f(a3[j])));
  uint4 ov;
  unsigned short* op = (unsigned short*)&ov;
  #pragma unroll
  for (int j = 0; j < 8; ++j) op[j] = o[j];
  *(uint4*)(P + (size_t)cell * 384 + c8) = ov;
}

// ---------------- fused QKV (+pooled KV) projection, depth-2 counted-vmcnt pipeline ----------------
// 3 LDS buffers; per iter: wait vmcnt(4) [tile t landed, t+1 in flight], barrier,
// stage t+2, compute t. Never drains all loads in the main loop (T3/T4 recipe).
__global__ __launch_bounds__(256) void mfma_proj_fused(
    const unsigned short* __restrict__ xb, const unsigned short* __restrict__ P,
    const unsigned short* __restrict__ Wt,
    const float* __restrict__ bq, const float* __restrict__ bk, const float* __restrict__ bv,
    unsigned short* __restrict__ Qb, unsigned short* __restrict__ Kcat,
    unsigned short* __restrict__ Vcat) {
  const int bid = blockIdx.x;
  const unsigned short* X;
  int wsel, colblk, yy; size_t off;
  if (bid < 2304) {
    const int xx = bid % 9; yy = bid / 9;
    X = xb; wsel = xx / 3; colblk = xx % 3; off = 0;
  } else {
    const int r = bid - 2304; const int xx = r % 6; yy = r / 6;
    X = P; wsel = 1 + xx / 3; colblk = xx % 3; off = (size_t)NTOK * 384;
  }
  const float* bias = (wsel == 0) ? bq : (wsel == 1) ? bk : bv;
  unsigned short* Y = ((wsel == 0) ? Qb : (wsel == 1) ? Kcat : Vcat) + off;
  const unsigned short* Wm = Wt + (size_t)wsel * 147456;
  const int n0 = colblk * 128;
  const int m0 = yy * 128;

  __shared__ __attribute__((aligned(16))) unsigned short As[3][128 * 32];
  __shared__ __attribute__((aligned(16))) unsigned short Bs[3][128 * 32];
  const int t = threadIdx.x;
  const int w = t >> 6, l = t & 63, l15 = l & 15, g = l >> 4;
  const int wm = w >> 1, wn = w & 1;
  const int srow = (w * 2) * 16 + (l >> 2), srow2 = (w * 2 + 1) * 16 + (l >> 2);
  const int skc = (l & 3) * 8;

  f32x4 acc[4][4];
  #pragma unroll
  for (int i = 0; i < 4; ++i)
    #pragma unroll
    for (int j = 0; j < 4; ++j) acc[i][j] = {0.f, 0.f, 0.f, 0.f};

  // prologue: stage tiles 0 and 1 (4 loads each per thread)
  #pragma unroll
  for (int pt = 0; pt < 2; ++pt) {
    const int k0 = pt * 32;
    gload16(X  + (size_t)(m0 + srow)  * 384 + k0 + skc, &As[pt][(w * 2)     * 512]);
    gload16(X  + (size_t)(m0 + srow2) * 384 + k0 + skc, &As[pt][(w * 2 + 1) * 512]);
    gload16(Wm + (size_t)(n0 + srow)  * 384 + k0 + skc, &Bs[pt][(w * 2)     * 512]);
    gload16(Wm + (size_t)(n0 + srow2) * 384 + k0 + skc, &Bs[pt][(w * 2 + 1) * 512]);
  }

  for (int kt = 0; kt < 12; ++kt) {
    if (kt < 11) asm volatile("s_waitcnt vmcnt(4)" ::: "memory");  // tile kt landed; kt+1 in flight
    else         asm volatile("s_waitcnt vmcnt(0)" ::: "memory");  // last tile
    __builtin_amdgcn_s_barrier();
    __builtin_amdgcn_sched_barrier(0);
    if (kt < 10) {   // stage kt+2 into buf (kt+2)%3 (its readers, compute kt-1, are past barrier)
      const int k0 = (kt + 2) * 32;
      const int bnext = (kt + 2) % 3;
      gload16(X  + (size_t)(m0 + srow)  * 384 + k0 + skc, &As[bnext][(w * 2)     * 512]);
      gload16(X  + (size_t)(m0 + srow2) * 384 + k0 + skc, &As[bnext][(w * 2 + 1) * 512]);
      gload16(Wm + (size_t)(n0 + srow)  * 384 + k0 + skc, &Bs[bnext][(w * 2)     * 512]);
      gload16(Wm + (size_t)(n0 + srow2) * 384 + k0 + skc, &Bs[bnext][(w * 2 + 1) * 512]);
    }
    const int cur = kt % 3;
    bf16x8 af[4], bfr[4];
    #pragma unroll
    for (int mi = 0; mi < 4; ++mi)
      af[mi] = *(const bf16x8*)(&As[cur][(wm * 64 + mi * 16 + l15) * 32 + g * 8]);
    #pragma unroll
    for (int nj = 0; nj < 4; ++nj)
      bfr[nj] = *(const bf16x8*)(&Bs[cur][(wn * 64 + nj * 16 + l15) * 32 + g * 8]);
    #pragma unroll
    for (int mi = 0; mi < 4; ++mi)
      #pragma unroll
      for (int nj = 0; nj < 4; ++nj)
        acc[mi][nj] = __builtin_amdgcn_mfma_f32_16x16x32_bf16(af[mi], bfr[nj], acc[mi][nj], 0, 0, 0);
  }

  float bv4[4];
  #pragma unroll
  for (int nj = 0; nj < 4; ++nj) bv4[nj] = bias[n0 + wn * 64 + nj * 16 + l15];
  #pragma unroll
  for (int mi = 0; mi < 4; ++mi)
    #pragma unroll
    for (int nj = 0; nj < 4; ++nj)
      #pragma unroll
      for (int r = 0; r < 4; ++r) {
        const size_t row = m0 + wm * 64 + mi * 16 + g * 4 + r;
        const size_t col = n0 + wn * 64 + nj * 16 + l15;
        Y[row * 384 + col] = f2bf(acc[mi][nj][r] + bv4[nj]);
      }
}

// ---------------- final output projection (f32 out), depth-2 pipeline ----------------
__global__ __launch_bounds__(256) void mfma_proj_out(const unsigned short* __restrict__ X,
                                                     const unsigned short* __restrict__ Wm,
                                                     const float* __restrict__ bias,
                                                     float* __restrict__ Y) {
  const int n0 = blockIdx.x * 128, m0 = blockIdx.y * 128;
  __shared__ __attribute__((aligned(16))) unsigned short As[3][128 * 32];
  __shared__ __attribute__((aligned(16))) unsigned short Bs[3][128 * 32];
  const int t = threadIdx.x;
  const int w = t >> 6, l = t & 63, l15 = l & 15, g = l >> 4;
  const int wm = w >> 1, wn = w & 1;
  const int srow = (w * 2) * 16 + (l >> 2), srow2 = (w * 2 + 1) * 16 + (l >> 2);
  const int skc = (l & 3) * 8;

  f32x4 acc[4][4];
  #pragma unroll
  for (int i = 0; i < 4; ++i)
    #pragma unroll
    for (int j = 0; j < 4; ++j) acc[i][j] = {0.f, 0.f, 0.f, 0.f};

  #pragma unroll
  for (int pt = 0; pt < 2; ++pt) {
    const int k0 = pt * 32;
    gload16(X  + (size_t)(m0 + srow)  * 384 + k0 + skc, &As[pt][(w * 2)     * 512]);
    gload16(X  + (size_t)(m0 + srow2) * 384 + k0 + skc, &As[pt][(w * 2 + 1) * 512]);
    gload16(Wm + (size_t)(n0 + srow)  * 384 + k0 + skc, &Bs[pt][(w * 2)     * 512]);
    gload16(Wm + (size_t)(n0 + srow2) * 384 + k0 + skc, &Bs[pt][(w * 2 + 1) * 512]);
  }

  for (int kt = 0; kt < 12; ++kt) {
    if (kt < 11) asm volatile("s_waitcnt vmcnt(4)" ::: "memory");
    else         asm volatile("s_waitcnt vmcnt(0)" ::: "memory");
    __builtin_amdgcn_s_barrier();
    __builtin_amdgcn_sched_barrier(0);
    if (kt < 10) {
      const int k0 = (kt + 2) * 32;
      const int bnext = (kt + 2) % 3;
      gload16(X  + (size_t)(m0 + srow)  * 384 + k0 + skc, &As[bnext][(w * 2)     * 512]);
      gload16(X  + (size_t)(m0 + srow2) * 384 + k0 + skc, &As[bnext][(w * 2 + 1) * 512]);
      gload16(Wm + (size_t)(n0 + srow)  * 384 + k0 + skc, &Bs[bnext][(w * 2)     * 512]);
      gload16(Wm + (size_t)(n0 + srow2) * 384 + k0 + skc, &Bs[bnext][(w * 2 + 1) * 512]);
    }
    const int cur = kt % 3;
    bf16x8 af[4], bfr[4];
    #pragma unroll
    for (int mi = 0; mi < 4; ++mi)
      af[mi] = *(const bf16x8*)(&As[cur][(wm * 64 + mi * 16 + l15) * 32 + g * 8]);
    #pragma unroll
    for (int nj = 0; nj < 4; ++nj)
      bfr[nj] = *(const bf16x8*)(&Bs[cur][(wn * 64 + nj * 16 + l15) * 32 + g * 8]);
    #pragma unroll
    for (int mi = 0; mi < 4; ++mi)
      #pragma unroll
      for (int nj = 0; nj < 4; ++nj)
        acc[mi][nj] = __builtin_amdgcn_mfma_f32_16x16x32_bf16(af[mi], bfr[nj], acc[mi][nj], 0, 0, 0);
  }

  float bv4[4];
  #pragma unroll
  for (int nj = 0; nj < 4; ++nj) bv4[nj] = bias[n0 + wn * 64 + nj * 16 + l15];
  #pragma unroll
  for (int mi = 0; mi < 4; ++mi)
    #pragma unroll
    for (int nj = 0; nj < 4; ++nj)
      #pragma unroll
      for (int r = 0; r < 4; ++r) {
        const size_t row = m0 + wm * 64 + mi * 16 + g * 4 + r;
        const size_t col = n0 + wn * 64 + nj * 16 + l15;
        Y[row * 384 + col] = acc[mi][nj][r] + bv4[nj];
      }
}

// ---------------- MFMA flash attention (R11 config, verified passing) ----------------
// no-max softmax, MFMA denominator, permlane P-transport, cvt_pk packing, XCD swizzle.
__global__ __launch_bounds__(256) void attn_mfma(const unsigned short* __restrict__ Qg,
                                                 const unsigned short* __restrict__ Kc,
                                                 const unsigned short* __restrict__ Vc,
                                                 const float* __restrict__ pb,
                                                 unsigned short* __restrict__ AttO) {
  __shared__ unsigned short kvb[768];   // token ids (< 45568)
  __shared__ float tb2s[12];
  __shared__ __attribute__((aligned(16))) unsigned short Ks[2][3072];    // [buf][ch][tok][8]
  __shared__ __attribute__((aligned(16))) unsigned short Vt[2][64 * 68]; // [buf][d+ones][kv]

  const int t = threadIdx.x;
  const int bid = blockIdx.x;
  const int head = (bid >> 3) & 7;
  const int win  = (bid & 7) + 8 * (bid >> 6);
  const int b = win >> 6, wrem = win & 63, wi = wrem >> 3, wj = wrem & 7;
  const int w = t >> 6, l = t & 63, l15 = l & 15, g = l >> 4;
  const int hb = head * 48;

  for (int j = t; j < 768; j += 256) {
    int o, within;
    if (j < 256)      { o = j >> 6;               within = j & 63; }
    else if (j < 512) { o = 4;                    within = j - 256; }
    else              { o = 5 + ((j - 512) >> 6); within = j & 63; }
    int tok;
    if (o == 4) {
      int r = within >> 4, c = within & 15;
      tok = (b * 128 + wi * 16 + r) * 128 + wj * 16 + c;
    } else {
      int di = o / 3 - 1, dj = o - (o / 3) * 3 - 1;
      int t0 = within >> 3, t1 = within & 7;
      int p0 = 8 * (1 + di + wi) + t0, p1 = 8 * (1 + dj + wj) + t1;
      tok = NTOK + (b * 80 + p0) * 80 + p1;
    }
    kvb[j] = (unsigned short)tok;
  }
  if (t < 12) {
    int o = (t < 4) ? t : ((t < 8) ? 4 : t - 3);
    tb2s[t] = (o == 4) ? 0.0f : (-pb[head * 9 + o] * LOG2E);
  }
  for (int idx = t; idx < 2 * 16 * 68; idx += 256) {
    const int bu = idx / 1088, rem = idx - bu * 1088;
    const int rr = rem / 68, cc = rem - rr * 68;
    Vt[bu][(48 + rr) * 68 + cc] = (rr == 0) ? 0x3F80 : 0;
  }

  const float SCALE2 = 0.14433756729740643f * LOG2E;  // 48^-0.5 * log2e
  const bf16x8 z8 = {0, 0, 0, 0, 0, 0, 0, 0};

  bf16x8 qf[4][2];
  #pragma unroll
  for (int nf = 0; nf < 4; ++nf) {
    const int tok = ((b * 128 + wi * 16 + w * 4 + nf) * 128 + wj * 16 + l15);
    const unsigned short* qp = Qg + (size_t)tok * 384 + hb;
    qf[nf][0] = *(const bf16x8*)(qp + g * 8);
    qf[nf][1] = (g < 2) ? *(const bf16x8*)(qp + 32 + g * 8) : z8;
  }

  f32x4 Oacc[4][4];
  #pragma unroll
  for (int mo = 0; mo < 4; ++mo)
    #pragma unroll
    for (int nf = 0; nf < 4; ++nf) Oacc[mo][nf] = {0.f, 0.f, 0.f, 0.f};

  __syncthreads();   // kvb / tb2s / ones rows ready

  uint4 va0, va1;
  {
    const int kvb0 = (int)kvb[l] * 384 + hb;
    gload16(Kc + kvb0 + w * 8, &Ks[0][w * 512]);
    if (w < 2) gload16(Kc + kvb0 + (4 + w) * 8, &Ks[0][(4 + w) * 512]);
    va0 = *(const uint4*)(Vc + kvb0 + w * 8);
    va1 = (w < 2) ? *(const uint4*)(Vc + kvb0 + (4 + w) * 8) : make_uint4(0, 0, 0, 0);
  }

  for (int T = 0; T < 12; ++T) {
    const int buf = T & 1;
    asm volatile("s_waitcnt vmcnt(0)" ::: "memory");   // K_T in LDS, V_T in regs
    {
      const unsigned short* u0 = (const unsigned short*)&va0;
      #pragma unroll
      for (int s = 0; s < 8; ++s) Vt[buf][(w * 8 + s) * 68 + l] = u0[s];
      if (w < 2) {
        const unsigned short* u1 = (const unsigned short*)&va1;
        #pragma unroll
        for (int s = 0; s < 8; ++s) Vt[buf][((4 + w) * 8 + s) * 68 + l] = u1[s];
      }
    }
    __syncthreads();   // all waves: K_T drained, V_T written, compute T-1 done
    if (T < 11) {
      const int kvb2 = (int)kvb[(T + 1) * 64 + l] * 384 + hb;
      gload16(Kc + kvb2 + w * 8, &Ks[buf ^ 1][w * 512]);
      if (w < 2) gload16(Kc + kvb2 + (4 + w) * 8, &Ks[buf ^ 1][(4 + w) * 512]);
      va0 = *(const uint4*)(Vc + kvb2 + w * 8);
      if (w < 2) va1 = *(const uint4*)(Vc + kvb2 + (4 + w) * 8);
    }

    const float tb = tb2s[T];
    #pragma unroll
    for (int h = 0; h < 2; ++h) {
      bf16x8 ka[2][2];
      #pragma unroll
      for (int mi = 0; mi < 2; ++mi) {
        const int krow = h * 32 + mi * 16 + l15;
        ka[mi][0] = *(const bf16x8*)&Ks[buf][g * 512 + krow * 8];
        ka[mi][1] = *(const bf16x8*)&Ks[buf][(4 + (g & 1)) * 512 + krow * 8];
      }
      f32x4 sf[2][4];
      #pragma unroll
      for (int mi = 0; mi < 2; ++mi)
        #pragma unroll
        for (int nf = 0; nf < 4; ++nf) sf[mi][nf] = {0.f, 0.f, 0.f, 0.f};
      __builtin_amdgcn_s_setprio(1);
      #pragma unroll
      for (int mi = 0; mi < 2; ++mi)
        #pragma unroll
        for (int nf = 0; nf < 4; ++nf) {
          sf[mi][nf] = __builtin_amdgcn_mfma_f32_16x16x32_bf16(ka[mi][0], qf[nf][0], sf[mi][nf], 0, 0, 0);
          sf[mi][nf] = __builtin_amdgcn_mfma_f32_16x16x32_bf16(ka[mi][1], qf[nf][1], sf[mi][nf], 0, 0, 0);
        }
      __builtin_amdgcn_s_setprio(0);

      bf16x8 pbf[4];
      #pragma unroll
      for (int nf = 0; nf < 4; ++nf) {
        float p[8];
        #pragma unroll
        for (int r = 0; r < 4; ++r) {
          p[r]     = fast_exp2(fmaf(sf[0][nf][r], SCALE2, tb));
          p[4 + r] = fast_exp2(fmaf(sf[1][nf][r], SCALE2, tb));
        }
        unsigned a0 = cvt_pk_bf16(p[0], p[1]);
        unsigned a1 = cvt_pk_bf16(p[2], p[3]);
        unsigned b0 = cvt_pk_bf16(p[4], p[5]);
        unsigned b1 = cvt_pk_bf16(p[6], p[7]);
        asm("v_permlane32_swap_b32 %0, %1" : "+v"(a0), "+v"(b0));
        asm("v_permlane32_swap_b32 %0, %1" : "+v"(a1), "+v"(b1));
        asm("v_permlane16_swap_b32 %0, %1" : "+v"(a0), "+v"(b0));
        asm("v_permlane16_swap_b32 %0, %1" : "+v"(a1), "+v"(b1));
        union { bf16x8 v; unsigned u[4]; } cv;
        cv.u[0] = a0; cv.u[1] = a1; cv.u[2] = b0; cv.u[3] = b1;
        pbf[nf] = cv.v;
      }

      #pragma unroll
      for (int mo = 0; mo < 4; ++mo) {
        const unsigned short* vp = &Vt[buf][(mo * 16 + l15) * 68 + h * 32 + g * 8];
        union { bf16x8 v; ushort4 u[2]; } cv;
        cv.u[0] = *(const ushort4*)vp;
        cv.u[1] = *(const ushort4*)(vp + 4);
        bf16x8 va = cv.v;
        __builtin_amdgcn_s_setprio(1);
        #pragma unroll
        for (int nf = 0; nf < 4; ++nf)
          Oacc[mo][nf] = __builtin_amdgcn_mfma_f32_16x16x32_bf16(va, pbf[nf], Oacc[mo][nf], 0, 0, 0);
        __builtin_amdgcn_s_setprio(0);
      }
    }
  }

  #pragma unroll
  for (int nf = 0; nf < 4; ++nf) {
    const float denom = __shfl(Oacc[3][nf][0], l15, 64);
    const float inv = 1.0f / denom;
    const int tok = ((b * 128 + wi * 16 + w * 4 + nf) * 128 + wj * 16 + l15);
    unsigned short* op = AttO + (size_t)tok * 384 + hb;
    #pragma unroll
    for (int mo = 0; mo < 3; ++mo) {
      uint2 u;
      u.x = cvt_pk_bf16(Oacc[mo][nf][0] * inv, Oacc[mo][nf][1] * inv);
      u.y = cvt_pk_bf16(Oacc[mo][nf][2] * inv, Oacc[mo][nf][3] * inv);
      *(uint2*)(op + mo * 16 + g * 4) = u;
    }
  }
}

extern "C" void kernel_launch(void* const* d_in, const int* in_sizes, int n_in,
                              void* d_out, int out_size, void* d_ws, size_t ws_size,
                              hipStream_t stream) {
  const float* x  = (const float*)d_in[0];
  const float* Wq = (const float*)d_in[1];
  const float* bq = (const float*)d_in[2];
  const float* Wk = (const float*)d_in[3];
  const float* bk = (const float*)d_in[4];
  const float* Wv = (const float*)d_in[5];
  const float* bv = (const float*)d_in[6];
  const float* Wo = (const float*)d_in[7];
  const float* bo = (const float*)d_in[8];
  const float* pb = (const float*)d_in[9];

  // ws layout (bytes), total ~106 MB (see R3 comment); Qb lives in d_out's first half.
  char* ws = (char*)d_ws;
  unsigned short* Wt   = (unsigned short*)(ws);
  unsigned short* P    = (unsigned short*)(ws + 1179648ull);
  unsigned short* Kcat = (unsigned short*)(ws + 11010048ull);
  unsigned short* Vcat = (unsigned short*)(ws + 46006272ull);
  unsigned short* xb   = (unsigned short*)(ws + 81002496ull);
  unsigned short* AttO = xb;
  unsigned short* Qb   = (unsigned short*)d_out;

  convert_x<<<6144, 256, 0, stream>>>(x, xb);
  pool_kernel<<<3200, 192, 0, stream>>>(xb, P);
  transpose_w<<<dim3(12, 12, 4), 256, 0, stream>>>(Wq, Wk, Wv, Wo, Wt);
  mfma_proj_fused<<<2904, 256, 0, stream>>>(xb, P, Wt, bq, bk, bv, Qb, Kcat, Vcat);
  attn_mfma<<<1024, 256, 0, stream>>>(Qb, Kcat, Vcat, pb, AttO);
  mfma_proj_out<<<dim3(3, 256), 256, 0, stream>>>(AttO, Wt + 3 * 147456, bo, (float*)d_out);
}